// Round 9
// baseline (75.673 us; speedup 1.0000x reference)
//
#include <hip/hip_runtime.h>
#include <math.h>

#define PCEN_EPS 1e-6f

constexpr int Bn = 64, Cn = 80, Tn = 8000;
constexpr int ROWS = Bn * Cn;     // 5120
constexpr int TILE = 2048;        // elements per wave (4 waves cover a row)
constexpr int HALO = 256;         // warm-up; w^256 ~ 2.9e-5 for s=0.04 -> err ~1e-3 << thr
constexpr int CH   = 256;         // sub-chunk = one contiguous 1KB load
constexpr int NQ   = TILE / CH;   // 8 chunks per wave

// pow for strictly-positive base on the HW transcendental pipe
__device__ __forceinline__ float fast_pow_pos(float b, float e) {
#if __has_builtin(__builtin_amdgcn_logf) && __has_builtin(__builtin_amdgcn_exp2f)
    return __builtin_amdgcn_exp2f(e * __builtin_amdgcn_logf(b));
#else
    return __exp2f(e * __log2f(b));
#endif
}

// R8 lesson: contiguous lanes helped (80->69us) but halo redundancy (+50%
// reads) and short 1024-elem tiles left ~30us of latency/issue overhead.
// This version: TILE=2048/wave (halo overhead 12.5%), 9 dwordx4 in flight,
// batched 8-chunk scans, rolling scalar carry (no Yx/T/G arrays).
__global__ __launch_bounds__(256, 4)
void pcen_kernel(const float* __restrict__ x,
                 const float* __restrict__ logit_s,
                 const float* __restrict__ alpha,
                 const float* __restrict__ delta,
                 const float* __restrict__ log_r,
                 float* __restrict__ out)
{
    const int lane = threadIdx.x & 63;
    const int wid  = threadIdx.x >> 6;
    const int row  = blockIdx.x;          // one block per row
    const int c    = row % Cn;

    const float* __restrict__ xrow = x   + (size_t)row * Tn;
    float* __restrict__ orow       = out + (size_t)row * Tn;
    const int St = wid * TILE;
    const int l4 = lane * 4;

    // ---- issue ALL global loads first (contiguous 1KB each; latencies overlap) ----
    float xv[NQ][4];
    #pragma unroll
    for (int q = 0; q < NQ; ++q) {
        const int tb = St + CH * q + l4;
        if (tb + 4 <= Tn) {
            const float4 p = *reinterpret_cast<const float4*>(xrow + tb);
            xv[q][0] = p.x; xv[q][1] = p.y; xv[q][2] = p.z; xv[q][3] = p.w;
        } else {
            xv[q][0] = xv[q][1] = xv[q][2] = xv[q][3] = 0.0f;
        }
    }
    float hx[4];
    const bool haloed = (wid != 0);
    if (haloed) {
        const int hb = St - HALO + l4;    // in-bounds (St >= 2048)
        const float4 p = *reinterpret_cast<const float4*>(xrow + hb);
        hx[0] = p.x; hx[1] = p.y; hx[2] = p.z; hx[3] = p.w;
    }

    // per-channel parameters (uniform; scheduled under the vmem waits)
    const float s  = 1.0f / (1.0f + __expf(-logit_s[c]));
    const float w  = 1.0f - s;
    const float a  = fminf(fmaxf(alpha[c], 0.1f), 1.0f);
    const float dd = fmaxf(delta[c], 0.1f);
    const float rr = fminf(fmaxf(__expf(log_r[c]), 0.05f), 1.5f);
    const float d_r = fast_pow_pos(dd, rr);
    const float na  = -a;

    // w4p[i] = w^(4*2^i), i=0..6 (w4p[6] = w^256), by repeated squaring
    float w4p[7];
    {
        const float w2 = w * w;
        w4p[0] = w2 * w2;
        #pragma unroll
        for (int i = 1; i < 7; ++i) w4p[i] = w4p[i - 1] * w4p[i - 1];
    }
    const float w256 = w4p[6];
    float w4L = 1.0f;           // w^(4*lane)
    #pragma unroll
    for (int b = 0; b < 6; ++b)
        if (lane & (1 << b)) w4L *= w4p[b];

    // relu, then PIN xv into VGPRs (prevents re-load/remat in the pointwise pass)
    #pragma unroll
    for (int q = 0; q < NQ; ++q)
        #pragma unroll
        for (int j = 0; j < 4; ++j) xv[q][j] = fmaxf(xv[q][j], 0.0f);
    #pragma unroll
    for (int q = 0; q < NQ; ++q)
        #pragma unroll
        for (int j = 0; j < 4; ++j) asm volatile("" : "+v"(xv[q][j]));

    // ---- carry-in P (IIR state just before tile start) ----
    float P;
    if (!haloed) {
        P = __shfl(xv[0][0], 0, 64);   // m_0 = w*P + s*x0 = x0 exactly
    } else {
        // per-lane Horner over 4 halo elems (carry 0)
        float yh = s * fmaxf(hx[0], 0.0f);
        #pragma unroll
        for (int j = 1; j < 4; ++j) yh = fmaf(yh, w, s * fmaxf(hx[j], 0.0f));
        // weight by w^(4*(63-lane)), butterfly-sum -> state after the 256-halo
        float wrev = 1.0f;
        const int rl = lane ^ 63;
        #pragma unroll
        for (int b = 0; b < 6; ++b)
            if (rl & (1 << b)) wrev *= w4p[b];
        float z = yh * wrev;
        #pragma unroll
        for (int st = 0; st < 6; ++st) z += __shfl_xor(z, 1 << st, 64);
        P = z;
    }

    // ---- 8 independent chunk scans (coef w^4), batched for ILP ----
    float Y[NQ];
    #pragma unroll
    for (int q = 0; q < NQ; ++q) {
        float y = s * xv[q][0];
        #pragma unroll
        for (int j = 1; j < 4; ++j) y = fmaf(y, w, s * xv[q][j]);
        Y[q] = y;
    }
    #pragma unroll
    for (int st = 0; st < 6; ++st) {
        float Yup[NQ];
        #pragma unroll
        for (int q = 0; q < NQ; ++q) Yup[q] = __shfl_up(Y[q], 1 << st, 64);
        #pragma unroll
        for (int q = 0; q < NQ; ++q) {
            const float cand = fmaf(w4p[st], Yup[q], Y[q]);
            Y[q] = (lane >= (1 << st)) ? cand : Y[q];
        }
    }

    // ---- pointwise pcen + contiguous stores, rolling chunk carry G ----
    float G = P;   // state just before chunk q start
    #pragma unroll
    for (int q = 0; q < NQ; ++q) {
        const float Yp = __shfl_up(Y[q], 1, 64);
        const float Yx = (lane == 0) ? 0.0f : Yp;       // exclusive scan
        const float Tq = __shfl(Y[q], 63, 64);          // chunk total
        const int tb = St + CH * q + l4;
        if (tb + 4 <= Tn) {
            float mm = fmaf(w4L, G, Yx);                // state before lane's 4 elems
            float o[4];
            #pragma unroll
            for (int j = 0; j < 4; ++j) {
                const float xx = xv[q][j];
                mm = fmaf(w, mm, s * xx);
                const float t = fast_pow_pos(PCEN_EPS + mm, na);
                o[j] = fast_pow_pos(fmaf(xx, t, dd), rr) - d_r;
            }
            *reinterpret_cast<float4*>(orow + tb) = make_float4(o[0], o[1], o[2], o[3]);
        }
        G = fmaf(w256, G, Tq);
    }
}

extern "C" void kernel_launch(void* const* d_in, const int* in_sizes, int n_in,
                              void* d_out, int out_size, void* d_ws, size_t ws_size,
                              hipStream_t stream) {
    const float* features = (const float*)d_in[0];
    const float* logit_s  = (const float*)d_in[1];
    const float* alpha    = (const float*)d_in[2];
    const float* delta    = (const float*)d_in[3];
    const float* log_r    = (const float*)d_in[4];
    float* out = (float*)d_out;

    // one block per row: wave w owns [w*2048, (w+1)*2048) with a 256-halo
    pcen_kernel<<<ROWS, 256, 0, stream>>>(features, logit_s, alpha, delta, log_r, out);
}

// Round 10
// 64.172 us; speedup vs baseline: 1.1792x; 1.1792x over previous
//
#include <hip/hip_runtime.h>
#include <math.h>

#define PCEN_EPS 1e-6f

constexpr int Bn = 64, Cn = 80, Tn = 8000;
constexpr int ROWS = Bn * Cn;   // 5120; one block per row
constexpr int WPR  = 4;         // waves per row
constexpr int SEG  = Tn / WPR;  // 2000 elements per wave
constexpr int CH   = 256;       // contiguous 1KB chunk (4 elems/lane)
constexpr int NQ   = 8;         // 7 full chunks + 208-elem tail
constexpr int TAIL   = SEG - 7 * CH;  // 208
constexpr int TLANES = TAIL / 4;      // 52 valid lanes in tail chunk

// pow for strictly-positive base on the HW transcendental pipe
__device__ __forceinline__ float fast_pow_pos(float b, float e) {
#if __has_builtin(__builtin_amdgcn_logf) && __has_builtin(__builtin_amdgcn_exp2f)
    return __builtin_amdgcn_exp2f(e * __builtin_amdgcn_logf(b));
#else
    return __exp2f(e * __log2f(b));
#endif
}

// R10 = R3's exact barrier carry (no halo reads) + R8's contiguous lanes +
// pinned x-residency. Phase A: batched chunk scans -> Yx[8], G[8] kept in
// regs. ONE __syncthreads. Phase B: pure VALU + stores (no shfl, no loads).
__global__ __launch_bounds__(256, 4)
void pcen_kernel(const float* __restrict__ x,
                 const float* __restrict__ logit_s,
                 const float* __restrict__ alpha,
                 const float* __restrict__ delta,
                 const float* __restrict__ log_r,
                 float* __restrict__ out)
{
    __shared__ float sm[WPR];
    const int lane = threadIdx.x & 63;
    const int wid  = threadIdx.x >> 6;
    const int row  = blockIdx.x;
    const int c    = row % Cn;

    const float* __restrict__ xs = x   + (size_t)row * Tn + wid * SEG;
    float* __restrict__ os       = out + (size_t)row * Tn + wid * SEG;
    const int l4 = lane * 4;

    // ---- all 8 contiguous loads issued up-front (8KB/wave in flight) ----
    float xv[NQ][4];
    #pragma unroll
    for (int q = 0; q < NQ; ++q) {
        const bool valid = (q < NQ - 1) || (lane < TLANES);
        if (valid) {
            const float4 p = *reinterpret_cast<const float4*>(xs + q * CH + l4);
            xv[q][0] = p.x; xv[q][1] = p.y; xv[q][2] = p.z; xv[q][3] = p.w;
        } else {
            xv[q][0] = xv[q][1] = xv[q][2] = xv[q][3] = 0.0f;
        }
    }

    // per-channel params (uniform; scheduled under the vmem waits)
    const float s  = 1.0f / (1.0f + __expf(-logit_s[c]));
    const float w  = 1.0f - s;
    const float a  = fminf(fmaxf(alpha[c], 0.1f), 1.0f);
    const float dd = fmaxf(delta[c], 0.1f);
    const float rr = fminf(fmaxf(__expf(log_r[c]), 0.05f), 1.5f);
    const float d_r = fast_pow_pos(dd, rr);
    const float na  = -a;

    // w4p[i] = w^(4*2^i), i=0..8 (w4p[8] = w^1024), repeated squaring
    float w4p[9];
    {
        const float w2 = w * w;
        w4p[0] = w2 * w2;
        #pragma unroll
        for (int i = 1; i < 9; ++i) w4p[i] = w4p[i - 1] * w4p[i - 1];
    }
    const float w256  = w4p[6];
    const float wT    = w4p[5] * w4p[4] * w4p[2];                       // w^208
    const float w2000 = w4p[8] * w4p[7] * w4p[6] * w4p[5] * w4p[4] * w4p[2];
    float w4L = 1.0f;   // w^(4*lane)
    #pragma unroll
    for (int b = 0; b < 6; ++b)
        if (lane & (1 << b)) w4L *= w4p[b];

    // relu then PIN: xv stays register-resident to the stores (blocks remat)
    #pragma unroll
    for (int q = 0; q < NQ; ++q)
        #pragma unroll
        for (int j = 0; j < 4; ++j) xv[q][j] = fmaxf(xv[q][j], 0.0f);
    #pragma unroll
    for (int q = 0; q < NQ; ++q)
        #pragma unroll
        for (int j = 0; j < 4; ++j) asm volatile("" : "+v"(xv[q][j]));

    // ---- phase A: 8 batched chunk scans; keep Yx[q], G[q] ----
    // wave 0 carry = relu(x[0]) so m_0 = w*x0 + s*x0 = x0 exactly
    float P = (wid == 0) ? __shfl(xv[0][0], 0, 64) : 0.0f;
    float Yx[NQ], G[NQ];
    float Y[NQ];
    #pragma unroll
    for (int q = 0; q < NQ; ++q) {
        float y = s * xv[q][0];
        #pragma unroll
        for (int j = 1; j < 4; ++j) y = fmaf(y, w, s * xv[q][j]);
        Y[q] = y;
    }
    #pragma unroll
    for (int st = 0; st < 6; ++st) {
        float Yup[NQ];
        #pragma unroll
        for (int q = 0; q < NQ; ++q) Yup[q] = __shfl_up(Y[q], 1 << st, 64);
        #pragma unroll
        for (int q = 0; q < NQ; ++q) {
            const float cand = fmaf(w4p[st], Yup[q], Y[q]);
            Y[q] = (lane >= (1 << st)) ? cand : Y[q];
        }
    }
    float Gc = P;
    #pragma unroll
    for (int q = 0; q < NQ; ++q) {
        const float Yp = __shfl_up(Y[q], 1, 64);
        Yx[q] = (lane == 0) ? 0.0f : Yp;                       // exclusive scan
        G[q]  = Gc;                                            // state before chunk q (local carry)
        const float Tq = __shfl(Y[q], (q == NQ - 1) ? (TLANES - 1) : 63, 64);
        Gc = fmaf((q == NQ - 1) ? wT : w256, Gc, Tq);
    }
    // Gc = wave-local segment end state (wave 0 includes x0 carry)

    // ---- cross-wave carry combine: ONE barrier ----
    if (lane == 0) sm[wid] = Gc;
    __syncthreads();
    const float A0 = sm[0];
    const float A1 = fmaf(w2000, A0, sm[1]);
    const float A2 = fmaf(w2000, A1, sm[2]);
    const float Pin = (wid == 1) ? A0 : (wid == 2) ? A1 : (wid == 3) ? A2 : 0.0f;

    // ---- phase B: pure VALU + contiguous stores (no shfl, no loads) ----
    float f = 1.0f;   // w^(256*q)
    #pragma unroll
    for (int q = 0; q < NQ; ++q) {
        const bool valid = (q < NQ - 1) || (lane < TLANES);
        const float Cq = fmaf(f, Pin, G[q]);        // corrected state before chunk q
        if (valid) {
            float mm = fmaf(w4L, Cq, Yx[q]);        // state before this lane's 4 elems
            float o[4];
            #pragma unroll
            for (int j = 0; j < 4; ++j) {
                const float xx = xv[q][j];
                mm = fmaf(w, mm, s * xx);
                const float t = fast_pow_pos(PCEN_EPS + mm, na);
                o[j] = fast_pow_pos(fmaf(xx, t, dd), rr) - d_r;
            }
            *reinterpret_cast<float4*>(os + q * CH + l4) =
                make_float4(o[0], o[1], o[2], o[3]);
        }
        f *= w256;
    }
}

extern "C" void kernel_launch(void* const* d_in, const int* in_sizes, int n_in,
                              void* d_out, int out_size, void* d_ws, size_t ws_size,
                              hipStream_t stream) {
    const float* features = (const float*)d_in[0];
    const float* logit_s  = (const float*)d_in[1];
    const float* alpha    = (const float*)d_in[2];
    const float* delta    = (const float*)d_in[3];
    const float* log_r    = (const float*)d_in[4];
    float* out = (float*)d_out;

    pcen_kernel<<<ROWS, WPR * 64, 0, stream>>>(features, logit_s, alpha, delta, log_r, out);
}